// Round 1
// baseline (248.136 us; speedup 1.0000x reference)
//
#include <hip/hip_runtime.h>

using f32x4 = __attribute__((ext_vector_type(4))) float;
using s16x8 = __attribute__((ext_vector_type(8))) short;
using u16x4 = __attribute__((ext_vector_type(4))) unsigned short;

#define AS1 __attribute__((address_space(1)))
#define AS3 __attribute__((address_space(3)))

__device__ __forceinline__ void gload16(const void* g, void* l) {
  __builtin_amdgcn_global_load_lds((const AS1 unsigned int*)g,
                                   (AS3 unsigned int*)l, 16, 0, 0);
}

__device__ __forceinline__ unsigned short f2bf(float f) {
  unsigned int u = __builtin_bit_cast(unsigned int, f);
  u += 0x7fffu + ((u >> 16) & 1u);   // round-to-nearest-even
  return (unsigned short)(u >> 16);
}

// ---------------- f32 -> bf16 convert ----------------
__global__ __launch_bounds__(256) void cvt_bf16(const float* __restrict__ in,
                                                unsigned short* __restrict__ out,
                                                int n4) {
  int i = blockIdx.x * blockDim.x + threadIdx.x;
  if (i >= n4) return;
  f32x4 v = ((const f32x4*)in)[i];
  u16x4 r;
#pragma unroll
  for (int j = 0; j < 4; ++j) r[j] = f2bf(v[j]);
  ((u16x4*)out)[i] = r;
}

// ---------------- GEMM: C = A * B^T  (A[M][K], B[N][K], bf16, K%64==0) -------
// MODE 0: out bf16 natural [row][col] (ldcE), scaled
// MODE 1: qv split: col<768 -> q natural [m][col] (ld 768); col>=768 -> Vt[col-768][m] (ld 4096)
// MODE 2: out f32 natural + bias
template <int MODE>
__global__ __launch_bounds__(256) void gemm_bt(
    const unsigned short* __restrict__ A, const unsigned short* __restrict__ B,
    int K, int ldaE, int ldbE, void* __restrict__ outQ,
    unsigned short* __restrict__ outV, const float* __restrict__ bias,
    float scale, int ldcE) {
  __shared__ __align__(16) unsigned short As[128 * 64];
  __shared__ __align__(16) unsigned short Bs[128 * 64];
  const int t = threadIdx.x;
  const int lane = t & 63;
  const int wid = t >> 6;
  const int wr = wid >> 1, wc = wid & 1;
  const int m0 = blockIdx.x * 128, n0 = blockIdx.y * 128;
  const int fr = lane & 15, fq = lane >> 4;

  f32x4 acc[4][4];
#pragma unroll
  for (int i = 0; i < 4; ++i)
#pragma unroll
    for (int j = 0; j < 4; ++j) acc[i][j] = (f32x4){0.f, 0.f, 0.f, 0.f};

  const char* Ab = (const char*)A;
  const char* Bb = (const char*)B;
  const size_t lda2 = (size_t)ldaE * 2, ldb2 = (size_t)ldbE * 2;

  for (int k0 = 0; k0 < K; k0 += 64) {
#pragma unroll
    for (int p = 0; p < 4; ++p) {
      int idx = p * 256 + t;
      int row = idx >> 3;
      int scb = ((idx & 7) << 4) ^ ((row & 7) << 4);  // pre-swizzled source col
      char* dstA = (char*)As + (p * 256 + (wid << 6)) * 16;  // wave-uniform
      char* dstB = (char*)Bs + (p * 256 + (wid << 6)) * 16;
      gload16(Ab + (size_t)(m0 + row) * lda2 + (size_t)k0 * 2 + scb, dstA);
      gload16(Bb + (size_t)(n0 + row) * ldb2 + (size_t)k0 * 2 + scb, dstB);
    }
    __syncthreads();

    s16x8 af[4][2], bfr[4][2];
#pragma unroll
    for (int mi = 0; mi < 4; ++mi)
#pragma unroll
      for (int kk = 0; kk < 2; ++kk) {
        int row = wr * 64 + mi * 16 + fr;
        int cb = (kk * 64 + (fq << 4)) ^ ((row & 7) << 4);
        af[mi][kk] = *(const s16x8*)((const char*)As + row * 128 + cb);
      }
#pragma unroll
    for (int ni = 0; ni < 4; ++ni)
#pragma unroll
      for (int kk = 0; kk < 2; ++kk) {
        int row = wc * 64 + ni * 16 + fr;
        int cb = (kk * 64 + (fq << 4)) ^ ((row & 7) << 4);
        bfr[ni][kk] = *(const s16x8*)((const char*)Bs + row * 128 + cb);
      }
#pragma unroll
    for (int kk = 0; kk < 2; ++kk)
#pragma unroll
      for (int mi = 0; mi < 4; ++mi)
#pragma unroll
        for (int ni = 0; ni < 4; ++ni)
          acc[mi][ni] = __builtin_amdgcn_mfma_f32_16x16x32_bf16(
              af[mi][kk], bfr[ni][kk], acc[mi][ni], 0, 0, 0);
    __syncthreads();
  }

#pragma unroll
  for (int mi = 0; mi < 4; ++mi) {
#pragma unroll
    for (int ni = 0; ni < 4; ++ni) {
      int row0 = m0 + wr * 64 + mi * 16 + (fq << 2);
      int col = n0 + wc * 64 + ni * 16 + fr;
      if (MODE == 2) {
        float bv = bias[col];
        float* o = (float*)outQ;
#pragma unroll
        for (int j = 0; j < 4; ++j)
          o[(size_t)(row0 + j) * ldcE + col] = acc[mi][ni][j] * scale + bv;
      } else if (MODE == 0) {
        unsigned short* o = (unsigned short*)outQ;
#pragma unroll
        for (int j = 0; j < 4; ++j)
          o[(size_t)(row0 + j) * ldcE + col] = f2bf(acc[mi][ni][j] * scale);
      } else {
        if (n0 < 768) {
          unsigned short* o = (unsigned short*)outQ;
#pragma unroll
          for (int j = 0; j < 4; ++j)
            o[(size_t)(row0 + j) * 768 + col] = f2bf(acc[mi][ni][j]);
        } else {
          u16x4 pk;
#pragma unroll
          for (int j = 0; j < 4; ++j) pk[j] = f2bf(acc[mi][ni][j]);
          *(u16x4*)(outV + (size_t)(col - 768) * 4096 + row0) = pk;
        }
      }
    }
  }
}

// ---------------- Flash attention ----------------
// S[n][m] = sum_d Qk[n][h*64+d] * Kq[m][h*64+d]   (Qk pre-scaled)
// y[n][h*64+d] = softmax_m(S) . Vt[h*64+d][m]
__global__ __launch_bounds__(256) void attn_kernel(
    const unsigned short* __restrict__ Qk,  // kbuf [4096][768]
    const unsigned short* __restrict__ Kq,  // qbuf [4096][768]
    const unsigned short* __restrict__ Vt,  // [768][4096]
    unsigned short* __restrict__ Y) {       // [4096][768]
  __shared__ __align__(16) unsigned short Ks[64 * 64];
  __shared__ __align__(16) unsigned short Vs[64 * 64];
  __shared__ __align__(16) unsigned short Ps[4 * 16 * 64];
  const int t = threadIdx.x, lane = t & 63, wid = t >> 6;
  const int fr = lane & 15, fq = lane >> 4;
  const int h = blockIdx.y;
  const int n0 = blockIdx.x * 64;

  s16x8 qf[2];
  {
    const size_t qrow = n0 + wid * 16 + fr;
#pragma unroll
    for (int kk = 0; kk < 2; ++kk)
      qf[kk] = *(const s16x8*)(Qk + qrow * 768 + h * 64 + kk * 32 + fq * 8);
  }
  f32x4 o[4];
#pragma unroll
  for (int c = 0; c < 4; ++c) o[c] = (f32x4){0.f, 0.f, 0.f, 0.f};
  float mold[4] = {-__builtin_inff(), -__builtin_inff(), -__builtin_inff(),
                   -__builtin_inff()};
  float lsum[4] = {0.f, 0.f, 0.f, 0.f};
  char* Pbase = (char*)Ps + wid * 2048;

  for (int m0 = 0; m0 < 4096; m0 += 64) {
#pragma unroll
    for (int p = 0; p < 2; ++p) {
      int idx = p * 256 + t;
      int row = idx >> 3;
      int scb = ((idx & 7) << 4) ^ ((row & 7) << 4);
      char* dk = (char*)Ks + (p * 256 + (wid << 6)) * 16;
      char* dv = (char*)Vs + (p * 256 + (wid << 6)) * 16;
      gload16((const char*)Kq + (size_t)(m0 + row) * 1536 + h * 128 + scb, dk);
      gload16((const char*)Vt + (size_t)(h * 64 + row) * 8192 + (size_t)m0 * 2 + scb, dv);
    }
    __syncthreads();

    f32x4 s[4];
#pragma unroll
    for (int c = 0; c < 4; ++c) s[c] = (f32x4){0.f, 0.f, 0.f, 0.f};
#pragma unroll
    for (int c = 0; c < 4; ++c)
#pragma unroll
      for (int kk = 0; kk < 2; ++kk) {
        int row = c * 16 + fr;
        int cb = (kk * 64 + (fq << 4)) ^ ((row & 7) << 4);
        s16x8 kf = *(const s16x8*)((const char*)Ks + row * 128 + cb);
        s[c] = __builtin_amdgcn_mfma_f32_16x16x32_bf16(qf[kk], kf, s[c], 0, 0, 0);
      }

    // wave-parallel online softmax; lane holds S[row=fq*4+j][col=c*16+fr]
    float mj[4];
#pragma unroll
    for (int j = 0; j < 4; ++j)
      mj[j] = fmaxf(fmaxf(s[0][j], s[1][j]), fmaxf(s[2][j], s[3][j]));
#pragma unroll
    for (int mask = 1; mask < 16; mask <<= 1)
#pragma unroll
      for (int j = 0; j < 4; ++j) mj[j] = fmaxf(mj[j], __shfl_xor(mj[j], mask));
    float sc[4], rs[4];
#pragma unroll
    for (int j = 0; j < 4; ++j) {
      float mn = fmaxf(mold[j], mj[j]);
      sc[j] = __expf(mold[j] - mn);
      mold[j] = mn;
      rs[j] = 0.f;
    }
#pragma unroll
    for (int c = 0; c < 4; ++c)
#pragma unroll
      for (int j = 0; j < 4; ++j) {
        float p = __expf(s[c][j] - mold[j]);
        rs[j] += p;
        int row = (fq << 2) + j;
        int colb = ((c * 16 + fr) * 2) ^ ((row & 7) << 4);
        *(unsigned short*)(Pbase + row * 128 + colb) = f2bf(p);
      }
#pragma unroll
    for (int mask = 1; mask < 16; mask <<= 1)
#pragma unroll
      for (int j = 0; j < 4; ++j) rs[j] += __shfl_xor(rs[j], mask);
#pragma unroll
    for (int j = 0; j < 4; ++j) lsum[j] = lsum[j] * sc[j] + rs[j];
#pragma unroll
    for (int c = 0; c < 4; ++c)
#pragma unroll
      for (int j = 0; j < 4; ++j) o[c][j] *= sc[j];

    // PV: A = P (per-wave LDS), B = Vt tile
#pragma unroll
    for (int kk = 0; kk < 2; ++kk) {
      int acb = (kk * 64 + (fq << 4)) ^ ((fr & 7) << 4);
      s16x8 pa = *(const s16x8*)(Pbase + fr * 128 + acb);
#pragma unroll
      for (int c = 0; c < 4; ++c) {
        int vrow = c * 16 + fr;
        int vcb = (kk * 64 + (fq << 4)) ^ ((vrow & 7) << 4);
        s16x8 vf = *(const s16x8*)((const char*)Vs + vrow * 128 + vcb);
        o[c] = __builtin_amdgcn_mfma_f32_16x16x32_bf16(pa, vf, o[c], 0, 0, 0);
      }
    }
    __syncthreads();
  }

#pragma unroll
  for (int c = 0; c < 4; ++c)
#pragma unroll
    for (int j = 0; j < 4; ++j) {
      float v = o[c][j] / lsum[j];
      size_t row = n0 + wid * 16 + (fq << 2) + j;
      int col = h * 64 + c * 16 + fr;
      Y[row * 768 + col] = f2bf(v);
    }
}

// ---------------- launch ----------------
extern "C" void kernel_launch(void* const* d_in, const int* in_sizes, int n_in,
                              void* d_out, int out_size, void* d_ws,
                              size_t ws_size, hipStream_t stream) {
  const float* x = (const float*)d_in[0];    // (4096, 768)
  const float* src = (const float*)d_in[1];  // (4096, 768)
  const float* Wqv = (const float*)d_in[2];  // (1536, 768)
  const float* Wk = (const float*)d_in[3];   // (768, 768)
  const float* Wp = (const float*)d_in[4];   // (768, 768)
  const float* bp = (const float*)d_in[5];   // (768,)
  float* out = (float*)d_out;

  char* ws = (char*)d_ws;
  unsigned short* srcb = (unsigned short*)(ws + 0);          // 4096x768
  unsigned short* xb   = (unsigned short*)(ws + 6291456);    // 4096x768
  unsigned short* wqvb = (unsigned short*)(ws + 12582912);   // 1536x768
  unsigned short* wkb  = (unsigned short*)(ws + 14942208);   // 768x768
  unsigned short* wpb  = (unsigned short*)(ws + 16121856);   // 768x768
  unsigned short* qbuf = (unsigned short*)(ws + 17301504);   // 4096x768
  unsigned short* vtbuf= (unsigned short*)(ws + 23592960);   // 768x4096
  unsigned short* kbuf = (unsigned short*)(ws + 29884416);   // 4096x768
  unsigned short* ybuf = (unsigned short*)(ws + 36175872);   // 4096x768

  cvt_bf16<<<3072, 256, 0, stream>>>(src, srcb, 786432);
  cvt_bf16<<<3072, 256, 0, stream>>>(x, xb, 786432);
  cvt_bf16<<<1152, 256, 0, stream>>>(Wqv, wqvb, 294912);
  cvt_bf16<<<576, 256, 0, stream>>>(Wk, wkb, 147456);
  cvt_bf16<<<576, 256, 0, stream>>>(Wp, wpb, 147456);

  // qv = src @ Wqv^T  -> q natural, v transposed
  gemm_bt<1><<<dim3(32, 12), 256, 0, stream>>>(srcb, wqvb, 768, 768, 768,
                                               (void*)qbuf, vtbuf, nullptr,
                                               1.0f, 768);
  // k = (x @ Wk^T) * SCALE
  gemm_bt<0><<<dim3(32, 6), 256, 0, stream>>>(xb, wkb, 768, 768, 768,
                                              (void*)kbuf, nullptr, nullptr,
                                              0.125f, 768);
  // attention
  attn_kernel<<<dim3(64, 12), 256, 0, stream>>>(kbuf, qbuf, vtbuf, ybuf);
  // out = y @ Wp^T + b
  gemm_bt<2><<<dim3(32, 6), 256, 0, stream>>>(ybuf, wpb, 768, 768, 768,
                                              (void*)out, nullptr, bp, 1.0f,
                                              768);
}

// Round 2
// 181.460 us; speedup vs baseline: 1.3674x; 1.3674x over previous
//
#include <hip/hip_runtime.h>

using f32x4 = __attribute__((ext_vector_type(4))) float;
using s16x8 = __attribute__((ext_vector_type(8))) short;
using u16x4 = __attribute__((ext_vector_type(4))) unsigned short;

#define AS1 __attribute__((address_space(1)))
#define AS3 __attribute__((address_space(3)))

__device__ __forceinline__ void gload16(const void* g, void* l) {
  __builtin_amdgcn_global_load_lds((const AS1 unsigned int*)g,
                                   (AS3 unsigned int*)l, 16, 0, 0);
}

__device__ __forceinline__ unsigned short f2bf(float f) {
  unsigned int u = __builtin_bit_cast(unsigned int, f);
  u += 0x7fffu + ((u >> 16) & 1u);   // round-to-nearest-even
  return (unsigned short)(u >> 16);
}

// ---------------- fused f32 -> bf16 convert (1 launch for all 5 tensors) ----
__global__ __launch_bounds__(256) void cvt_bf16_multi(
    const float* __restrict__ i0, const float* __restrict__ i1,
    const float* __restrict__ i2, const float* __restrict__ i3,
    const float* __restrict__ i4, unsigned short* __restrict__ o0,
    unsigned short* __restrict__ o1, unsigned short* __restrict__ o2,
    unsigned short* __restrict__ o3, unsigned short* __restrict__ o4) {
  int b = blockIdx.x;
  const float* in;
  unsigned short* out;
  int base, n4;
  if (b < 3072) { in = i0; out = o0; base = b; n4 = 786432; }
  else if (b < 6144) { in = i1; out = o1; base = b - 3072; n4 = 786432; }
  else if (b < 7296) { in = i2; out = o2; base = b - 6144; n4 = 294912; }
  else if (b < 7872) { in = i3; out = o3; base = b - 7296; n4 = 147456; }
  else { in = i4; out = o4; base = b - 7872; n4 = 147456; }
  int i = base * 256 + threadIdx.x;
  if (i >= n4) return;
  f32x4 v = ((const f32x4*)in)[i];
  u16x4 r;
#pragma unroll
  for (int j = 0; j < 4; ++j) r[j] = f2bf(v[j]);
  ((u16x4*)out)[i] = r;
}

// ---------------- GEMM: C = A * B^T  (A[M][K], B[N][K], bf16, K%64==0) -------
// MODE 0: out bf16 natural [row][col] (ldcE), scaled
// MODE 1: qv split: col<768 -> q natural [m][col] (ld 768); col>=768 -> Vt[col-768][m] (ld 4096)
// MODE 2: out f32 natural + bias
template <int MODE>
__global__ __launch_bounds__(256) void gemm_bt(
    const unsigned short* __restrict__ A, const unsigned short* __restrict__ B,
    int K, int ldaE, int ldbE, void* __restrict__ outQ,
    unsigned short* __restrict__ outV, const float* __restrict__ bias,
    float scale, int ldcE) {
  __shared__ __align__(16) unsigned short As[128 * 64];
  __shared__ __align__(16) unsigned short Bs[128 * 64];
  const int t = threadIdx.x;
  const int lane = t & 63;
  const int wid = t >> 6;
  const int wr = wid >> 1, wc = wid & 1;
  const int m0 = blockIdx.x * 128, n0 = blockIdx.y * 128;
  const int fr = lane & 15, fq = lane >> 4;

  f32x4 acc[4][4];
#pragma unroll
  for (int i = 0; i < 4; ++i)
#pragma unroll
    for (int j = 0; j < 4; ++j) acc[i][j] = (f32x4){0.f, 0.f, 0.f, 0.f};

  const char* Ab = (const char*)A;
  const char* Bb = (const char*)B;
  const size_t lda2 = (size_t)ldaE * 2, ldb2 = (size_t)ldbE * 2;

  for (int k0 = 0; k0 < K; k0 += 64) {
#pragma unroll
    for (int p = 0; p < 4; ++p) {
      int idx = p * 256 + t;
      int row = idx >> 3;
      int scb = ((idx & 7) << 4) ^ ((row & 7) << 4);  // pre-swizzled source col
      char* dstA = (char*)As + (p * 256 + (wid << 6)) * 16;  // wave-uniform
      char* dstB = (char*)Bs + (p * 256 + (wid << 6)) * 16;
      gload16(Ab + (size_t)(m0 + row) * lda2 + (size_t)k0 * 2 + scb, dstA);
      gload16(Bb + (size_t)(n0 + row) * ldb2 + (size_t)k0 * 2 + scb, dstB);
    }
    __syncthreads();

    s16x8 af[4][2], bfr[4][2];
#pragma unroll
    for (int mi = 0; mi < 4; ++mi)
#pragma unroll
      for (int kk = 0; kk < 2; ++kk) {
        int row = wr * 64 + mi * 16 + fr;
        int cb = (kk * 64 + (fq << 4)) ^ ((row & 7) << 4);
        af[mi][kk] = *(const s16x8*)((const char*)As + row * 128 + cb);
      }
#pragma unroll
    for (int ni = 0; ni < 4; ++ni)
#pragma unroll
      for (int kk = 0; kk < 2; ++kk) {
        int row = wc * 64 + ni * 16 + fr;
        int cb = (kk * 64 + (fq << 4)) ^ ((row & 7) << 4);
        bfr[ni][kk] = *(const s16x8*)((const char*)Bs + row * 128 + cb);
      }
    __builtin_amdgcn_s_setprio(1);
#pragma unroll
    for (int kk = 0; kk < 2; ++kk)
#pragma unroll
      for (int mi = 0; mi < 4; ++mi)
#pragma unroll
        for (int ni = 0; ni < 4; ++ni)
          acc[mi][ni] = __builtin_amdgcn_mfma_f32_16x16x32_bf16(
              af[mi][kk], bfr[ni][kk], acc[mi][ni], 0, 0, 0);
    __builtin_amdgcn_s_setprio(0);
    __syncthreads();
  }

#pragma unroll
  for (int mi = 0; mi < 4; ++mi) {
#pragma unroll
    for (int ni = 0; ni < 4; ++ni) {
      int row0 = m0 + wr * 64 + mi * 16 + (fq << 2);
      int col = n0 + wc * 64 + ni * 16 + fr;
      if (MODE == 2) {
        float bv = bias[col];
        float* o = (float*)outQ;
#pragma unroll
        for (int j = 0; j < 4; ++j)
          o[(size_t)(row0 + j) * ldcE + col] = acc[mi][ni][j] * scale + bv;
      } else if (MODE == 0) {
        unsigned short* o = (unsigned short*)outQ;
#pragma unroll
        for (int j = 0; j < 4; ++j)
          o[(size_t)(row0 + j) * ldcE + col] = f2bf(acc[mi][ni][j] * scale);
      } else {
        if (n0 < 768) {
          unsigned short* o = (unsigned short*)outQ;
#pragma unroll
          for (int j = 0; j < 4; ++j)
            o[(size_t)(row0 + j) * 768 + col] = f2bf(acc[mi][ni][j]);
        } else {
          u16x4 pk;
#pragma unroll
          for (int j = 0; j < 4; ++j) pk[j] = f2bf(acc[mi][ni][j]);
          *(u16x4*)(outV + (size_t)(col - 768) * 4096 + row0) = pk;
        }
      }
    }
  }
}

// ---------------- Flash attention (swapped QK^T, lane-local softmax) --------
// Qk = kbuf [4096][768], pre-scaled by 0.125/ln2 (log2-domain softmax)
// Kq = qbuf [4096][768];  Vt [768][4096];  Y [4096][768]
// S^T[m][n] via mfma(A=Ktile, B=Qfrag): lane holds m = 16c+4*fq+reg, n = fr.
__global__ __launch_bounds__(256) void attn_kernel(
    const unsigned short* __restrict__ Qk, const unsigned short* __restrict__ Kq,
    const unsigned short* __restrict__ Vt, unsigned short* __restrict__ Y) {
  __shared__ __align__(16) unsigned short Ks[2][64 * 64];
  __shared__ __align__(16) unsigned short Vs[2][64 * 64];
  __shared__ __align__(16) unsigned short Ps[4 * 16 * 64];
  const int t = threadIdx.x, lane = t & 63, wid = t >> 6;
  const int fr = lane & 15, fq = lane >> 4;
  const int h = blockIdx.y;
  const int n0 = blockIdx.x * 64;
  const int swz = (fr & 7) << 4;

  // Q fragment (flash-Q = k-projection rows), hoisted
  s16x8 qf[2];
  {
    const size_t qrow = n0 + wid * 16 + fr;
#pragma unroll
    for (int kk = 0; kk < 2; ++kk)
      qf[kk] = *(const s16x8*)(Qk + qrow * 768 + h * 64 + kk * 32 + fq * 8);
  }

  f32x4 o[4];
#pragma unroll
  for (int c = 0; c < 4; ++c) o[c] = (f32x4){0.f, 0.f, 0.f, 0.f};
  float mold = -__builtin_inff();
  float lsum = 0.f;
  char* Pb = (char*)Ps + wid * 2048 + fr * 128;

  auto stage = [&](int buf, int m0) {
#pragma unroll
    for (int p = 0; p < 2; ++p) {
      int idx = p * 256 + t;
      int row = idx >> 3;
      int scb = ((idx & 7) << 4) ^ ((row & 7) << 4);
      char* dk = (char*)Ks[buf] + (p * 256 + (wid << 6)) * 16;
      char* dv = (char*)Vs[buf] + (p * 256 + (wid << 6)) * 16;
      gload16((const char*)Kq + (size_t)(m0 + row) * 1536 + h * 128 + scb, dk);
      gload16((const char*)Vt + (size_t)(h * 64 + row) * 8192 + (size_t)m0 * 2 + scb, dv);
    }
  };

  stage(0, 0);
  __syncthreads();

  for (int it = 0; it < 64; ++it) {
    const int buf = it & 1;
    if (it < 63) stage(buf ^ 1, (it + 1) * 64);  // prefetch; drained at barrier

    // ---- QK^T (swapped): s[c] holds S^T[m=16c+4fq+reg][n=fr]
    f32x4 s[4];
#pragma unroll
    for (int c = 0; c < 4; ++c) s[c] = (f32x4){0.f, 0.f, 0.f, 0.f};
    const char* Ksb = (const char*)Ks[buf];
    const char* Vsb = (const char*)Vs[buf];
    __builtin_amdgcn_s_setprio(1);
#pragma unroll
    for (int kk = 0; kk < 2; ++kk)
#pragma unroll
      for (int c = 0; c < 4; ++c) {
        int row = c * 16 + fr;
        s16x8 kf = *(const s16x8*)(Ksb + row * 128 +
                                   ((kk * 64 + (fq << 4)) ^ ((row & 7) << 4)));
        s[c] = __builtin_amdgcn_mfma_f32_16x16x32_bf16(kf, qf[kk], s[c], 0, 0, 0);
      }
    __builtin_amdgcn_s_setprio(0);

    // ---- lane-local online softmax (log2 domain), row = fr
    float pmax = s[0][0];
#pragma unroll
    for (int c = 0; c < 4; ++c)
#pragma unroll
      for (int j = 0; j < 4; ++j) pmax = fmaxf(pmax, s[c][j]);
    pmax = fmaxf(pmax, __shfl_xor(pmax, 16));
    pmax = fmaxf(pmax, __shfl_xor(pmax, 32));

    if (!__all(pmax - mold <= 8.f)) {   // defer-max (THR=8 in log2 units)
      float mn = fmaxf(mold, pmax);
      float sc = __builtin_exp2f(mold - mn);  // -inf -> 0 on first tile
      mold = mn;
      lsum *= sc;
      float sco[4];
#pragma unroll
      for (int j = 0; j < 4; ++j) sco[j] = __shfl(sc, 4 * fq + j);
#pragma unroll
      for (int c = 0; c < 4; ++c)
#pragma unroll
        for (int j = 0; j < 4; ++j) o[c][j] *= sco[j];
    }

    float rs = 0.f;
    float p[4][4];
#pragma unroll
    for (int c = 0; c < 4; ++c)
#pragma unroll
      for (int j = 0; j < 4; ++j) {
        p[c][j] = __builtin_exp2f(s[c][j] - mold);
        rs += p[c][j];
      }
    // pack P -> per-wave LDS [n=fr][m], swizzled; 4x ds_write_b64
#pragma unroll
    for (int c = 0; c < 4; ++c) {
      unsigned int w0, w1;
      asm("v_cvt_pk_bf16_f32 %0, %1, %2" : "=v"(w0) : "v"(p[c][0]), "v"(p[c][1]));
      asm("v_cvt_pk_bf16_f32 %0, %1, %2" : "=v"(w1) : "v"(p[c][2]), "v"(p[c][3]));
      uint2 u;
      u.x = w0;
      u.y = w1;
      *(uint2*)(Pb + ((32 * c + 8 * fq) ^ swz)) = u;
    }
    rs += __shfl_xor(rs, 16);
    rs += __shfl_xor(rs, 32);
    lsum += rs;

    // ---- PV: o[c] += P[n][m] * Vt[d][m]^T ; lane holds y[n=4fq+reg][d=16c+fr]
    __builtin_amdgcn_s_setprio(1);
#pragma unroll
    for (int kk = 0; kk < 2; ++kk) {
      s16x8 pa = *(const s16x8*)(Pb + ((kk * 64 + (fq << 4)) ^ swz));
#pragma unroll
      for (int c = 0; c < 4; ++c) {
        int vrow = c * 16 + fr;
        s16x8 vf = *(const s16x8*)(Vsb + vrow * 128 +
                                   ((kk * 64 + (fq << 4)) ^ ((vrow & 7) << 4)));
        o[c] = __builtin_amdgcn_mfma_f32_16x16x32_bf16(pa, vf, o[c], 0, 0, 0);
      }
    }
    __builtin_amdgcn_s_setprio(0);
    __syncthreads();
  }

  // epilogue: redistribute 1/lsum from stat layout (row=fr) to o layout
  float inv = 1.0f / lsum;
  float invo[4];
#pragma unroll
  for (int j = 0; j < 4; ++j) invo[j] = __shfl(inv, 4 * fq + j);
#pragma unroll
  for (int c = 0; c < 4; ++c)
#pragma unroll
    for (int j = 0; j < 4; ++j) {
      size_t row = n0 + wid * 16 + (fq << 2) + j;
      int col = h * 64 + c * 16 + fr;
      Y[row * 768 + col] = f2bf(o[c][j] * invo[j]);
    }
}

// ---------------- launch ----------------
extern "C" void kernel_launch(void* const* d_in, const int* in_sizes, int n_in,
                              void* d_out, int out_size, void* d_ws,
                              size_t ws_size, hipStream_t stream) {
  const float* x = (const float*)d_in[0];    // (4096, 768)
  const float* src = (const float*)d_in[1];  // (4096, 768)
  const float* Wqv = (const float*)d_in[2];  // (1536, 768)
  const float* Wk = (const float*)d_in[3];   // (768, 768)
  const float* Wp = (const float*)d_in[4];   // (768, 768)
  const float* bp = (const float*)d_in[5];   // (768,)
  float* out = (float*)d_out;

  char* ws = (char*)d_ws;
  unsigned short* srcb = (unsigned short*)(ws + 0);          // 4096x768
  unsigned short* xb   = (unsigned short*)(ws + 6291456);    // 4096x768
  unsigned short* wqvb = (unsigned short*)(ws + 12582912);   // 1536x768
  unsigned short* wkb  = (unsigned short*)(ws + 14942208);   // 768x768
  unsigned short* wpb  = (unsigned short*)(ws + 16121856);   // 768x768
  unsigned short* qbuf = (unsigned short*)(ws + 17301504);   // 4096x768
  unsigned short* vtbuf= (unsigned short*)(ws + 23592960);   // 768x4096
  unsigned short* kbuf = (unsigned short*)(ws + 29884416);   // 4096x768
  unsigned short* ybuf = (unsigned short*)(ws + 36175872);   // 4096x768

  cvt_bf16_multi<<<8448, 256, 0, stream>>>(src, x, Wqv, Wk, Wp, srcb, xb, wqvb,
                                           wkb, wpb);

  // qv = src @ Wqv^T  -> q natural, v transposed
  gemm_bt<1><<<dim3(32, 12), 256, 0, stream>>>(srcb, wqvb, 768, 768, 768,
                                               (void*)qbuf, vtbuf, nullptr,
                                               1.0f, 768);
  // k = (x @ Wk^T) * SCALE / ln(2)   (log2-domain softmax)
  gemm_bt<0><<<dim3(32, 6), 256, 0, stream>>>(xb, wkb, 768, 768, 768,
                                              (void*)kbuf, nullptr, nullptr,
                                              0.18033688f, 768);
  // attention
  attn_kernel<<<dim3(64, 12), 256, 0, stream>>>(kbuf, qbuf, vtbuf, ybuf);
  // out = y @ Wp^T + b
  gemm_bt<2><<<dim3(32, 6), 256, 0, stream>>>(ybuf, wpb, 768, 768, 768,
                                              (void*)out, nullptr, bp, 1.0f,
                                              768);
}